// Round 11
// baseline (43.602 us; speedup 1.0000x reference)
//
#include <hip/hip_runtime.h>

#define BATCH 512
#define PIX   65536
#define NOUT  512
#define COUT  4
#define NCLS  10

#define KC    2048                // K-chunk (pixels) per block
#define NKC   (PIX / KC)          // 32
#define NRG   (BATCH / 8)         // 64 row-groups (8 rows per block)
#define AWROW 4112                // LDS Aw row stride bytes: 2048*2 + 16 pad

// must match __builtin_amdgcn_cvt_pkrtz's return type exactly
typedef __fp16 half2_t __attribute__((ext_vector_type(2)));

#if __has_builtin(__builtin_amdgcn_fdot2)
__device__ __forceinline__ float fdot2f(half2_t a, half2_t b, float c) {
    return __builtin_amdgcn_fdot2(a, b, c, false);
}
#else
__device__ __forceinline__ float fdot2f(half2_t a, half2_t b, float c) {
    return c + (float)a[0] * (float)b[0] + (float)a[1] * (float)b[1];
}
#endif

// ---------------------------------------------------------------------------
// Single fused kernel: out[n,k] = sum_p x[n,p] * Weff_h[seg[p]][k] + cst[k]
// Block = 8 rows x 2048-px chunk; grid = 64 rowg x 32 kc = 2048.
// Phase A: every block computes Weff (f16, packed) for all 512 regions into
//          LDS (W_fgl/W_fc are L2-hot; 40 FMAs per j). kc==0 also cst.
// Phase B: build Aw[k][2048] f16 in LDS from seg chunk (pair-packed dwords).
// Phase C: dot loop — float4 x (coalesced), ds_read_b64 Aw (2-way, free),
//          cvt_pkrtz + v_dot2_f32_f16 into 20 accumulators.
// Phase D: LDS tree-reduce; 80 atomics/block; kc==0 adds cst once per row.
// out must be zeroed before (memset); no other pre-init.
// ---------------------------------------------------------------------------
__global__ __launch_bounds__(256) void fused_gemm_kernel(
    const float* __restrict__ x, const int* __restrict__ seg,
    const float* __restrict__ W_fgl, const float* __restrict__ b_fgl,
    const float* __restrict__ W_fc,  const float* __restrict__ b_fc,
    float* __restrict__ out)
{
    __shared__ unsigned wh[NOUT * 5];                 // 10240 B packed Weff f16
    __shared__ __align__(16) char awmem[10 * AWROW];  // 41120 B Aw / partials
    __shared__ float red[4 * NCLS];
    __shared__ float cs[NCLS];

    const int t    = threadIdx.x;
    const int rowg = blockIdx.x & (NRG - 1);
    const int kc   = blockIdx.x >> 6;
    const int pc   = kc * KC;

    // ---------------- phase A: Weff + (cst partials) ----------------
    float cpart[NCLS];
#pragma unroll
    for (int k = 0; k < NCLS; ++k) cpart[k] = 0.f;

#pragma unroll
    for (int jj = 0; jj < 2; ++jj) {
        const int j = jj * 256 + t;
        float wf[COUT], bf[COUT];
#pragma unroll
        for (int c = 0; c < COUT; ++c) {
            wf[c] = W_fgl[c * NOUT + j];
            bf[c] = b_fgl[c * NOUT + j];
        }
        float wv[NCLS];
#pragma unroll
        for (int k = 0; k < NCLS; ++k) {
            float w = 0.f, cb = 0.f;
#pragma unroll
            for (int c = 0; c < COUT; ++c) {
                const float wfc = W_fc[(c * NOUT + j) * NCLS + k];
                w  += wf[c] * wfc;
                cb += bf[c] * wfc;
            }
            wv[k] = w;
            cpart[k] += cb;
        }
#pragma unroll
        for (int k5 = 0; k5 < 5; ++k5) {
            const half2_t h = __builtin_amdgcn_cvt_pkrtz(wv[2 * k5], wv[2 * k5 + 1]);
            wh[j * 5 + k5] = __builtin_bit_cast(unsigned, h);
        }
    }

    // cst shuffle reduce (cheap; final value used only by kc==0 blocks)
#pragma unroll
    for (int k = 0; k < NCLS; ++k)
#pragma unroll
        for (int off = 32; off; off >>= 1)
            cpart[k] += __shfl_down(cpart[k], off);
    if ((t & 63) == 0) {
#pragma unroll
        for (int k = 0; k < NCLS; ++k) red[(t >> 6) * NCLS + k] = cpart[k];
    }
    __syncthreads();                       // wh + red ready
    if (t < NCLS) {
        float s = b_fc[t];
#pragma unroll
        for (int w2 = 0; w2 < 4; ++w2) s += red[w2 * NCLS + t];
        cs[t] = s;                         // read in phase D (syncs between)
    }

    // ---------------- phase B: build Aw[k][2048] from seg ----------------
#pragma unroll
    for (int i = 0; i < 4; ++i) {
        const int pr = i * 256 + t;        // pixel pair 0..1023
        const int2 js = *(const int2*)(seg + pc + pr * 2);
        const unsigned* wa = &wh[js.x * 5];
        const unsigned* wb = &wh[js.y * 5];
#pragma unroll
        for (int k5 = 0; k5 < 5; ++k5) {
            const unsigned a = wa[k5], b = wb[k5];
            *(unsigned*)(awmem + (2 * k5)     * AWROW + pr * 4) =
                (a & 0xffffu) | (b << 16);
            *(unsigned*)(awmem + (2 * k5 + 1) * AWROW + pr * 4) =
                (a >> 16) | (b & 0xffff0000u);
        }
    }
    __syncthreads();

    // ---------------- phase C: dot products ----------------
    const int w = t >> 6, lane = t & 63;
    const int r0 = rowg * 8 + w * 2;
    const float4* __restrict__ xa = (const float4*)(x + (size_t)r0 * PIX + pc);
    const float4* __restrict__ xb = (const float4*)(x + (size_t)(r0 + 1) * PIX + pc);

    float acc0[NCLS] = {}, acc1[NCLS] = {};
#pragma unroll 2
    for (int i = 0; i < KC / 4 / 64; ++i) {          // 8 iterations
        const int px4 = i * 64 + lane;
        const float4 va = xa[px4];
        const float4 vb = xb[px4];
        uint2 awv[NCLS];
#pragma unroll
        for (int k = 0; k < NCLS; ++k)
            awv[k] = *(const uint2*)(awmem + k * AWROW + px4 * 8);
        const half2_t a0 = __builtin_amdgcn_cvt_pkrtz(va.x, va.y);
        const half2_t a1 = __builtin_amdgcn_cvt_pkrtz(va.z, va.w);
        const half2_t b0 = __builtin_amdgcn_cvt_pkrtz(vb.x, vb.y);
        const half2_t b1 = __builtin_amdgcn_cvt_pkrtz(vb.z, vb.w);
#pragma unroll
        for (int k = 0; k < NCLS; ++k) {
            const half2_t wlo = __builtin_bit_cast(half2_t, awv[k].x);
            const half2_t whi = __builtin_bit_cast(half2_t, awv[k].y);
            acc0[k] = fdot2f(a1, whi, fdot2f(a0, wlo, acc0[k]));
            acc1[k] = fdot2f(b1, whi, fdot2f(b0, wlo, acc1[k]));
        }
    }
    __syncthreads();   // all Aw reads done -> overlay partials

    // ---------------- phase D: reduce + atomics ----------------
    float* part = (float*)awmem;           // [20][264]
#pragma unroll
    for (int k = 0; k < NCLS; ++k) {
        part[k * 264 + t]        = acc0[k];
        part[(10 + k) * 264 + t] = acc1[k];
    }
    __syncthreads();

    if (t < 80) {
        const int w2 = t / 20, j = t % 20;
        const float4* src = (const float4*)(part + j * 264 + w2 * 64);
        float4 s4 = src[0];
#pragma unroll
        for (int q = 1; q < 16; ++q) {
            const float4 v = src[q];
            s4.x += v.x; s4.y += v.y; s4.z += v.z; s4.w += v.w;
        }
        const int r = j / 10, k = j % 10;
        float s = (s4.x + s4.y) + (s4.z + s4.w);
        if (kc == 0) s += cs[k];           // cst added exactly once per (row,k)
        unsafeAtomicAdd(&out[(rowg * 8 + w2 * 2 + r) * NCLS + k], s);
    }
}

// ---------------------------------------------------------------------------
extern "C" void kernel_launch(void* const* d_in, const int* in_sizes, int n_in,
                              void* d_out, int out_size, void* d_ws, size_t ws_size,
                              hipStream_t stream)
{
    const float* x     = (const float*)d_in[0];
    const float* W_fgl = (const float*)d_in[1];
    const float* b_fgl = (const float*)d_in[2];
    const float* W_fc  = (const float*)d_in[3];
    const float* b_fc  = (const float*)d_in[4];
    const int*   seg   = (const int*)d_in[5];
    float*       out   = (float*)d_out;

    hipMemsetAsync(out, 0, (size_t)BATCH * NCLS * sizeof(float), stream);

    fused_gemm_kernel<<<dim3(NRG * NKC), 256, 0, stream>>>(
        x, seg, W_fgl, b_fgl, W_fc, b_fc, out);
}

// Round 12
// 34.966 us; speedup vs baseline: 1.2470x; 1.2470x over previous
//
#include <hip/hip_runtime.h>

#define BATCH 512
#define PIX   65536
#define NOUT  512
#define COUT  4
#define NCLS  10

#define KC    2048                // K-chunk (pixels) per block
#define NKC   (PIX / KC)          // 32
#define NRG   (BATCH / 8)         // 64 row-groups (8 rows per block)
#define AWROW 4112                // LDS Aw row stride bytes: 2048*2 + 16 pad

// must match __builtin_amdgcn_cvt_pkrtz's return type exactly
typedef __fp16 half2_t __attribute__((ext_vector_type(2)));

#if __has_builtin(__builtin_amdgcn_fdot2)
__device__ __forceinline__ float fdot2f(half2_t a, half2_t b, float c) {
    return __builtin_amdgcn_fdot2(a, b, c, false);
}
#else
__device__ __forceinline__ float fdot2f(half2_t a, half2_t b, float c) {
    return c + (float)a[0] * (float)b[0] + (float)a[1] * (float)b[1];
}
#endif

// ---------------------------------------------------------------------------
// 0: Weff_h[j] (10 x f16 packed in 5 uints) = sum_c W_fgl[c,j] * W_fc[c*NOUT+j,:]
//    out[n,k] <- cst[k]  (bias term; gemm then atomically accumulates)
// One block; runs once, off the critical path cost-wise.
// ---------------------------------------------------------------------------
__global__ __launch_bounds__(512) void weff_kernel(
    const float* __restrict__ W_fgl, const float* __restrict__ b_fgl,
    const float* __restrict__ W_fc,  const float* __restrict__ b_fc,
    unsigned* __restrict__ Weff_h, float* __restrict__ out)
{
    const int j = threadIdx.x;          // 0..511

    float wf[COUT], bf[COUT];
#pragma unroll
    for (int c = 0; c < COUT; ++c) {
        wf[c] = W_fgl[c * NOUT + j];
        bf[c] = b_fgl[c * NOUT + j];
    }

    float wv[NCLS], cpart[NCLS];
#pragma unroll
    for (int k = 0; k < NCLS; ++k) {
        float w = 0.f, cb = 0.f;
#pragma unroll
        for (int c = 0; c < COUT; ++c) {
            const float wfc = W_fc[(c * NOUT + j) * NCLS + k];
            w  += wf[c] * wfc;
            cb += bf[c] * wfc;
        }
        wv[k]    = w;
        cpart[k] = cb;
    }

#pragma unroll
    for (int k5 = 0; k5 < 5; ++k5) {
        const half2_t h = __builtin_amdgcn_cvt_pkrtz(wv[2 * k5], wv[2 * k5 + 1]);
        Weff_h[j * 5 + k5] = __builtin_bit_cast(unsigned, h);
    }

#pragma unroll
    for (int k = 0; k < NCLS; ++k)
#pragma unroll
        for (int off = 32; off; off >>= 1)
            cpart[k] += __shfl_down(cpart[k], off);

    __shared__ float red[8 * NCLS];
    __shared__ float cs[NCLS];
    if ((j & 63) == 0) {
#pragma unroll
        for (int k = 0; k < NCLS; ++k) red[(j >> 6) * NCLS + k] = cpart[k];
    }
    __syncthreads();
    if (j < NCLS) {
        float s = b_fc[j];
#pragma unroll
        for (int w = 0; w < 8; ++w) s += red[w * NCLS + j];
        cs[j] = s;
    }
    __syncthreads();
    const float csl = cs[j % NCLS];      // j<512, pattern repeats every 10
    for (int i = j; i < BATCH * NCLS; i += 512) out[i] = cs[i % NCLS];
    (void)csl;
}

// ---------------------------------------------------------------------------
// 1: fused Aw-build + GEMM: out[n,k] += sum_p x[n,p] * Weff_h[seg[p]][k]
// Block = 8 rows x 2048-px chunk; grid = 64 x 32 = 2048; 51.4KB LDS -> 3/CU.
// Phase S: stage Weff_h (10KB) into LDS — coalesced, L2-hot broadcast.
// Phase B: build Aw[k][2048] f16 in LDS from seg chunk (pair-packed dwords;
//          random LDS dword gathers ~2 lanes/bank = free).
// Phase C: float4 x (coalesced 1KB/instr) + ds_read_b64 Aw (2-way, free) +
//          cvt_pkrtz + v_dot2_f32_f16 into 20 accumulators.
// Phase D: LDS tree-reduce, 80 atomics/block into cst-pre-initialized out.
// ---------------------------------------------------------------------------
__global__ __launch_bounds__(256) void gemm_kernel(
    const float* __restrict__ x, const int* __restrict__ seg,
    const unsigned* __restrict__ Weff_h, float* __restrict__ out)
{
    __shared__ unsigned wh[NOUT * 5];                 // 10240 B
    __shared__ __align__(16) char awmem[10 * AWROW];  // 41120 B

    const int t    = threadIdx.x;
    const int rowg = blockIdx.x & (NRG - 1);
    const int kc   = blockIdx.x >> 6;
    const int pc   = kc * KC;

    // ---- phase S: stage packed Weff ----
#pragma unroll
    for (int i = 0; i < 10; ++i) wh[i * 256 + t] = Weff_h[i * 256 + t];
    __syncthreads();

    // ---- phase B: build Aw[k][2048] from seg ----
#pragma unroll
    for (int i = 0; i < 4; ++i) {
        const int pr = i * 256 + t;        // pixel pair 0..1023
        const int2 js = *(const int2*)(seg + pc + pr * 2);
        const unsigned* wa = &wh[js.x * 5];
        const unsigned* wb = &wh[js.y * 5];
#pragma unroll
        for (int k5 = 0; k5 < 5; ++k5) {
            const unsigned a = wa[k5], b = wb[k5];
            *(unsigned*)(awmem + (2 * k5)     * AWROW + pr * 4) =
                (a & 0xffffu) | (b << 16);
            *(unsigned*)(awmem + (2 * k5 + 1) * AWROW + pr * 4) =
                (a >> 16) | (b & 0xffff0000u);
        }
    }
    __syncthreads();

    // ---- phase C: dot products ----
    const int w = t >> 6, lane = t & 63;
    const int r0 = rowg * 8 + w * 2;
    const float4* __restrict__ xa = (const float4*)(x + (size_t)r0 * PIX + pc);
    const float4* __restrict__ xb = (const float4*)(x + (size_t)(r0 + 1) * PIX + pc);

    float acc0[NCLS] = {}, acc1[NCLS] = {};
#pragma unroll 2
    for (int i = 0; i < KC / 4 / 64; ++i) {          // 8 iterations
        const int px4 = i * 64 + lane;
        const float4 va = xa[px4];
        const float4 vb = xb[px4];
        uint2 awv[NCLS];
#pragma unroll
        for (int k = 0; k < NCLS; ++k)
            awv[k] = *(const uint2*)(awmem + k * AWROW + px4 * 8);
        const half2_t a0 = __builtin_amdgcn_cvt_pkrtz(va.x, va.y);
        const half2_t a1 = __builtin_amdgcn_cvt_pkrtz(va.z, va.w);
        const half2_t b0 = __builtin_amdgcn_cvt_pkrtz(vb.x, vb.y);
        const half2_t b1 = __builtin_amdgcn_cvt_pkrtz(vb.z, vb.w);
#pragma unroll
        for (int k = 0; k < NCLS; ++k) {
            const half2_t wlo = __builtin_bit_cast(half2_t, awv[k].x);
            const half2_t whi = __builtin_bit_cast(half2_t, awv[k].y);
            acc0[k] = fdot2f(a1, whi, fdot2f(a0, wlo, acc0[k]));
            acc1[k] = fdot2f(b1, whi, fdot2f(b0, wlo, acc1[k]));
        }
    }
    __syncthreads();   // all Aw reads done -> overlay partials

    // ---- phase D: reduce + atomics ----
    float* part = (float*)awmem;           // [20][264]
#pragma unroll
    for (int k = 0; k < NCLS; ++k) {
        part[k * 264 + t]        = acc0[k];
        part[(10 + k) * 264 + t] = acc1[k];
    }
    __syncthreads();

    if (t < 80) {
        const int w2 = t / 20, j = t % 20;
        const float4* src = (const float4*)(part + j * 264 + w2 * 64);
        float4 s4 = src[0];
#pragma unroll
        for (int q = 1; q < 16; ++q) {
            const float4 v = src[q];
            s4.x += v.x; s4.y += v.y; s4.z += v.z; s4.w += v.w;
        }
        const float s = (s4.x + s4.y) + (s4.z + s4.w);
        const int r = j / 10, k = j % 10;
        unsafeAtomicAdd(&out[(rowg * 8 + w2 * 2 + r) * NCLS + k], s);
    }
}

// ---------------------------------------------------------------------------
extern "C" void kernel_launch(void* const* d_in, const int* in_sizes, int n_in,
                              void* d_out, int out_size, void* d_ws, size_t ws_size,
                              hipStream_t stream)
{
    const float* x     = (const float*)d_in[0];
    const float* W_fgl = (const float*)d_in[1];
    const float* b_fgl = (const float*)d_in[2];
    const float* W_fc  = (const float*)d_in[3];
    const float* b_fc  = (const float*)d_in[4];
    const int*   seg   = (const int*)d_in[5];
    float*       out   = (float*)d_out;

    unsigned* Weff_h = (unsigned*)d_ws;    // 10 KB

    weff_kernel<<<dim3(1),         512, 0, stream>>>(W_fgl, b_fgl, W_fc, b_fc,
                                                     Weff_h, out);
    gemm_kernel<<<dim3(NRG * NKC), 256, 0, stream>>>(x, seg, Weff_h, out);
}

// Round 13
// 34.351 us; speedup vs baseline: 1.2693x; 1.0179x over previous
//
#include <hip/hip_runtime.h>

#define BATCH 512
#define PIX   65536
#define NOUT  512
#define COUT  4
#define NCLS  10

#define KC    1024                // K-chunk (pixels) per block
#define NKC   (PIX / KC)          // 64
#define NRG   (BATCH / 8)         // 64 row-groups (8 rows per block)
#define AWROW 2064                // LDS Aw row stride bytes: 1024*2 + 16 pad
#define WH_B  10240               // packed Weff bytes
#define ARENA (WH_B + 10 * AWROW) // 30880 B shared arena

// must match __builtin_amdgcn_cvt_pkrtz's return type exactly
typedef __fp16 half2_t __attribute__((ext_vector_type(2)));

#if __has_builtin(__builtin_amdgcn_fdot2)
__device__ __forceinline__ float fdot2f(half2_t a, half2_t b, float c) {
    return __builtin_amdgcn_fdot2(a, b, c, false);
}
#else
__device__ __forceinline__ float fdot2f(half2_t a, half2_t b, float c) {
    return c + (float)a[0] * (float)b[0] + (float)a[1] * (float)b[1];
}
#endif

// ---------------------------------------------------------------------------
// 0: Weff_h[j] (10 x f16 packed in 5 uints) = sum_c W_fgl[c,j] * W_fc[c*NOUT+j,:]
//    out[n,k] <- cst[k]  (bias term; gemm then atomically accumulates)
// ---------------------------------------------------------------------------
__global__ __launch_bounds__(512) void weff_kernel(
    const float* __restrict__ W_fgl, const float* __restrict__ b_fgl,
    const float* __restrict__ W_fc,  const float* __restrict__ b_fc,
    unsigned* __restrict__ Weff_h, float* __restrict__ out)
{
    const int j = threadIdx.x;          // 0..511

    float wf[COUT], bf[COUT];
#pragma unroll
    for (int c = 0; c < COUT; ++c) {
        wf[c] = W_fgl[c * NOUT + j];
        bf[c] = b_fgl[c * NOUT + j];
    }

    float wv[NCLS], cpart[NCLS];
#pragma unroll
    for (int k = 0; k < NCLS; ++k) {
        float w = 0.f, cb = 0.f;
#pragma unroll
        for (int c = 0; c < COUT; ++c) {
            const float wfc = W_fc[(c * NOUT + j) * NCLS + k];
            w  += wf[c] * wfc;
            cb += bf[c] * wfc;
        }
        wv[k]    = w;
        cpart[k] = cb;
    }

#pragma unroll
    for (int k5 = 0; k5 < 5; ++k5) {
        const half2_t h = __builtin_amdgcn_cvt_pkrtz(wv[2 * k5], wv[2 * k5 + 1]);
        Weff_h[j * 5 + k5] = __builtin_bit_cast(unsigned, h);
    }

#pragma unroll
    for (int k = 0; k < NCLS; ++k)
#pragma unroll
        for (int off = 32; off; off >>= 1)
            cpart[k] += __shfl_down(cpart[k], off);

    __shared__ float red[8 * NCLS];
    __shared__ float cs[NCLS];
    if ((j & 63) == 0) {
#pragma unroll
        for (int k = 0; k < NCLS; ++k) red[(j >> 6) * NCLS + k] = cpart[k];
    }
    __syncthreads();
    if (j < NCLS) {
        float s = b_fc[j];
#pragma unroll
        for (int w = 0; w < 8; ++w) s += red[w * NCLS + j];
        cs[j] = s;
    }
    __syncthreads();
    for (int i = j; i < BATCH * NCLS; i += 512) out[i] = cs[i % NCLS];
}

// ---------------------------------------------------------------------------
// 1: fused Aw-build + GEMM: out[n,k] += sum_p x[n,p] * Weff_h[seg[p]][k]
// Block = 8 rows x 1024-px chunk; grid = 64 rowg x 64 kc = 4096 (kc-major).
// 30.9KB LDS + launch_bounds(256,5) -> 5 blocks/CU: S/B/C/D phases of
// different blocks interleave, keeping HBM + DS pipes simultaneously fed.
// ---------------------------------------------------------------------------
__global__ __launch_bounds__(256, 5) void gemm_kernel(
    const float* __restrict__ x, const int* __restrict__ seg,
    const unsigned* __restrict__ Weff_h, float* __restrict__ out)
{
    __shared__ __align__(16) char smem[ARENA];        // wh | awmem ; D overlays
    unsigned* wh    = (unsigned*)smem;                // 10240 B
    char*     awmem = smem + WH_B;                    // 10 * 2064 B

    const int t    = threadIdx.x;
    const int rowg = blockIdx.x & (NRG - 1);
    const int kc   = blockIdx.x >> 6;
    const int pc   = kc * KC;

    // ---- phase S: stage packed Weff (coalesced, L2-hot) ----
#pragma unroll
    for (int i = 0; i < 10; ++i) wh[i * 256 + t] = Weff_h[i * 256 + t];
    __syncthreads();

    // ---- phase B: build Aw[k][1024] f16 from seg chunk ----
#pragma unroll
    for (int i = 0; i < 2; ++i) {
        const int pr = i * 256 + t;        // pixel pair 0..511
        const int2 js = *(const int2*)(seg + pc + pr * 2);
        const unsigned* wa = &wh[js.x * 5];
        const unsigned* wb = &wh[js.y * 5];
#pragma unroll
        for (int k5 = 0; k5 < 5; ++k5) {
            const unsigned a = wa[k5], b = wb[k5];
            *(unsigned*)(awmem + (2 * k5)     * AWROW + pr * 4) =
                (a & 0xffffu) | (b << 16);
            *(unsigned*)(awmem + (2 * k5 + 1) * AWROW + pr * 4) =
                (a >> 16) | (b & 0xffff0000u);
        }
    }
    __syncthreads();

    // ---- phase C: dot products ----
    const int w = t >> 6, lane = t & 63;
    const int r0 = rowg * 8 + w * 2;
    const float4* __restrict__ xa = (const float4*)(x + (size_t)r0 * PIX + pc);
    const float4* __restrict__ xb = (const float4*)(x + (size_t)(r0 + 1) * PIX + pc);

    float acc0[NCLS] = {}, acc1[NCLS] = {};
#pragma unroll 2
    for (int i = 0; i < KC / 4 / 64; ++i) {          // 4 iterations
        const int px4 = i * 64 + lane;
        const float4 va = xa[px4];
        const float4 vb = xb[px4];
        uint2 awv[NCLS];
#pragma unroll
        for (int k = 0; k < NCLS; ++k)
            awv[k] = *(const uint2*)(awmem + k * AWROW + px4 * 8);
        const half2_t a0 = __builtin_amdgcn_cvt_pkrtz(va.x, va.y);
        const half2_t a1 = __builtin_amdgcn_cvt_pkrtz(va.z, va.w);
        const half2_t b0 = __builtin_amdgcn_cvt_pkrtz(vb.x, vb.y);
        const half2_t b1 = __builtin_amdgcn_cvt_pkrtz(vb.z, vb.w);
#pragma unroll
        for (int k = 0; k < NCLS; ++k) {
            const half2_t wlo = __builtin_bit_cast(half2_t, awv[k].x);
            const half2_t whi = __builtin_bit_cast(half2_t, awv[k].y);
            acc0[k] = fdot2f(a1, whi, fdot2f(a0, wlo, acc0[k]));
            acc1[k] = fdot2f(b1, whi, fdot2f(b0, wlo, acc1[k]));
        }
    }
    __syncthreads();   // all Aw/wh reads done -> overlay partials

    // ---- phase D: reduce + atomics ----
    float* part = (float*)smem;            // [20][264] = 21120 B <= ARENA
#pragma unroll
    for (int k = 0; k < NCLS; ++k) {
        part[k * 264 + t]        = acc0[k];
        part[(10 + k) * 264 + t] = acc1[k];
    }
    __syncthreads();

    if (t < 80) {
        const int w2 = t / 20, j = t % 20;
        const float4* src = (const float4*)(part + j * 264 + w2 * 64);
        float4 s4 = src[0];
#pragma unroll
        for (int q = 1; q < 16; ++q) {
            const float4 v = src[q];
            s4.x += v.x; s4.y += v.y; s4.z += v.z; s4.w += v.w;
        }
        const float s = (s4.x + s4.y) + (s4.z + s4.w);
        const int r = j / 10, k = j % 10;
        unsafeAtomicAdd(&out[(rowg * 8 + w2 * 2 + r) * NCLS + k], s);
    }
}

// ---------------------------------------------------------------------------
extern "C" void kernel_launch(void* const* d_in, const int* in_sizes, int n_in,
                              void* d_out, int out_size, void* d_ws, size_t ws_size,
                              hipStream_t stream)
{
    const float* x     = (const float*)d_in[0];
    const float* W_fgl = (const float*)d_in[1];
    const float* b_fgl = (const float*)d_in[2];
    const float* W_fc  = (const float*)d_in[3];
    const float* b_fc  = (const float*)d_in[4];
    const int*   seg   = (const int*)d_in[5];
    float*       out   = (float*)d_out;

    unsigned* Weff_h = (unsigned*)d_ws;    // 10 KB

    weff_kernel<<<dim3(1),         512, 0, stream>>>(W_fgl, b_fgl, W_fc, b_fc,
                                                     Weff_h, out);
    gemm_kernel<<<dim3(NRG * NKC), 256, 0, stream>>>(x, seg, Weff_h, out);
}

// Round 14
// 32.934 us; speedup vs baseline: 1.3239x; 1.0430x over previous
//
#include <hip/hip_runtime.h>

#define BATCH 512
#define PIX   65536
#define NOUT  512
#define COUT  4
#define NCLS  10

#define KC    1024                // K-chunk (pixels) per gemm block
#define NKC   (PIX / KC)          // 64
#define NRG   (BATCH / 8)         // 64 row-groups (8 rows per block)

// must match __builtin_amdgcn_cvt_pkrtz's return type exactly
typedef __fp16 half2_t __attribute__((ext_vector_type(2)));

#if __has_builtin(__builtin_amdgcn_fdot2)
__device__ __forceinline__ float fdot2f(half2_t a, half2_t b, float c) {
    return __builtin_amdgcn_fdot2(a, b, c, false);
}
#else
__device__ __forceinline__ float fdot2f(half2_t a, half2_t b, float c) {
    return c + (float)a[0] * (float)b[0] + (float)a[1] * (float)b[1];
}
#endif

// ---------------------------------------------------------------------------
// 0: build AwT[k][p] (f16, [10][65536]) = Weff[seg[p]][k], pair-packed dword
//    stores (coalesced). Each of 128 blocks redundantly computes Weff into
//    LDS (W_fc 80KB L2-hot; ~10MB aggregate — cheap). Block 0 additionally
//    computes cst[k] and initializes out[n,k] = cst[k].
// ---------------------------------------------------------------------------
__global__ __launch_bounds__(256) void awbuild_kernel(
    const float* __restrict__ W_fgl, const float* __restrict__ b_fgl,
    const float* __restrict__ W_fc,  const float* __restrict__ b_fc,
    const int* __restrict__ seg, unsigned* __restrict__ AwT32,
    float* __restrict__ out)
{
    __shared__ unsigned wh[NOUT * 5];      // 10240 B packed Weff f16
    __shared__ float red[4 * NCLS];
    __shared__ float cs[NCLS];

    const int t = threadIdx.x, bid = blockIdx.x;

    // ---- phase A: Weff (all blocks, redundant) + cst partials ----
    float cpart[NCLS];
#pragma unroll
    for (int k = 0; k < NCLS; ++k) cpart[k] = 0.f;

#pragma unroll
    for (int jj = 0; jj < 2; ++jj) {
        const int j = jj * 256 + t;
        float wf[COUT], bf[COUT];
#pragma unroll
        for (int c = 0; c < COUT; ++c) {
            wf[c] = W_fgl[c * NOUT + j];
            bf[c] = b_fgl[c * NOUT + j];
        }
        float wv[NCLS];
#pragma unroll
        for (int k = 0; k < NCLS; ++k) {
            float w = 0.f, cb = 0.f;
#pragma unroll
            for (int c = 0; c < COUT; ++c) {
                const float wfc = W_fc[(c * NOUT + j) * NCLS + k];
                w  += wf[c] * wfc;
                cb += bf[c] * wfc;
            }
            wv[k] = w;
            cpart[k] += cb;
        }
#pragma unroll
        for (int k5 = 0; k5 < 5; ++k5) {
            const half2_t h = __builtin_amdgcn_cvt_pkrtz(wv[2 * k5], wv[2 * k5 + 1]);
            wh[j * 5 + k5] = __builtin_bit_cast(unsigned, h);
        }
    }
    __syncthreads();

    // ---- phase B: pair-pack this block's 512-pixel window into AwT ----
    const int pp = bid * 256 + t;          // pixel-pair index
    const int2 js = *(const int2*)(seg + pp * 2);
    const unsigned* wa = &wh[js.x * 5];
    const unsigned* wb = &wh[js.y * 5];
#pragma unroll
    for (int k5 = 0; k5 < 5; ++k5) {
        const unsigned a = wa[k5], b = wb[k5];
        AwT32[(2 * k5)     * (PIX / 2) + pp] = (a & 0xffffu) | (b << 16);
        AwT32[(2 * k5 + 1) * (PIX / 2) + pp] = (a >> 16) | (b & 0xffff0000u);
    }

    // ---- block 0: cst + out init ----
    if (bid == 0) {
#pragma unroll
        for (int k = 0; k < NCLS; ++k)
#pragma unroll
            for (int off = 32; off; off >>= 1)
                cpart[k] += __shfl_down(cpart[k], off);
        if ((t & 63) == 0) {
#pragma unroll
            for (int k = 0; k < NCLS; ++k) red[(t >> 6) * NCLS + k] = cpart[k];
        }
        __syncthreads();
        if (t < NCLS) {
            float s = b_fc[t];
#pragma unroll
            for (int w2 = 0; w2 < 4; ++w2) s += red[w2 * NCLS + t];
            cs[t] = s;
        }
        __syncthreads();
        for (int i = t; i < BATCH * NCLS; i += 256) out[i] = cs[i % NCLS];
    }
}

// ---------------------------------------------------------------------------
// 1: GEMM: out[n,k] += sum_p x[n,p] * AwT[k][p]
// Block = 8 rows x 1024-px chunk; grid = 64 rowg x 64 kc (kc-major -> AwT and
// seg chunks L2-hot). NO LDS staging: Aw read straight from global as uint4
// (8 px per instr, L2/L3-resident 1.3MB). DS pipe only carries the final
// reduce. Inner loop: 10 uint4 + 4 float4 loads, 80 fdot2 per wave-iter.
// ---------------------------------------------------------------------------
__global__ __launch_bounds__(256, 4) void gemm_kernel(
    const float* __restrict__ x, const unsigned short* __restrict__ AwT,
    float* __restrict__ out)
{
    __shared__ __align__(16) float part[20 * 264];   // 21120 B

    const int t = threadIdx.x, w = t >> 6, lane = t & 63;
    const int rowg = blockIdx.x & (NRG - 1);
    const int kc   = blockIdx.x >> 6;
    const int pc   = kc * KC;
    const int r0   = rowg * 8 + w * 2;

    const float4* __restrict__ xa = (const float4*)(x + (size_t)r0 * PIX + pc);
    const float4* __restrict__ xb = (const float4*)(x + (size_t)(r0 + 1) * PIX + pc);

    float acc0[NCLS] = {}, acc1[NCLS] = {};
#pragma unroll
    for (int i = 0; i < KC / 512; ++i) {             // 2 iterations
        const int e8 = i * 64 + lane;                // 8-pixel group index
        uint4 awq[NCLS];
#pragma unroll
        for (int k = 0; k < NCLS; ++k)
            awq[k] = *(const uint4*)(AwT + (size_t)k * PIX + pc + e8 * 8);
        const float4 va0 = xa[e8 * 2], va1 = xa[e8 * 2 + 1];
        const float4 vb0 = xb[e8 * 2], vb1 = xb[e8 * 2 + 1];
        const half2_t a01 = __builtin_amdgcn_cvt_pkrtz(va0.x, va0.y);
        const half2_t a23 = __builtin_amdgcn_cvt_pkrtz(va0.z, va0.w);
        const half2_t a45 = __builtin_amdgcn_cvt_pkrtz(va1.x, va1.y);
        const half2_t a67 = __builtin_amdgcn_cvt_pkrtz(va1.z, va1.w);
        const half2_t b01 = __builtin_amdgcn_cvt_pkrtz(vb0.x, vb0.y);
        const half2_t b23 = __builtin_amdgcn_cvt_pkrtz(vb0.z, vb0.w);
        const half2_t b45 = __builtin_amdgcn_cvt_pkrtz(vb1.x, vb1.y);
        const half2_t b67 = __builtin_amdgcn_cvt_pkrtz(vb1.z, vb1.w);
#pragma unroll
        for (int k = 0; k < NCLS; ++k) {
            const half2_t w01 = __builtin_bit_cast(half2_t, awq[k].x);
            const half2_t w23 = __builtin_bit_cast(half2_t, awq[k].y);
            const half2_t w45 = __builtin_bit_cast(half2_t, awq[k].z);
            const half2_t w67 = __builtin_bit_cast(half2_t, awq[k].w);
            acc0[k] = fdot2f(a67, w67, fdot2f(a45, w45,
                      fdot2f(a23, w23, fdot2f(a01, w01, acc0[k]))));
            acc1[k] = fdot2f(b67, w67, fdot2f(b45, w45,
                      fdot2f(b23, w23, fdot2f(b01, w01, acc1[k]))));
        }
    }

    // ---- reduce + atomics (identical layout to R12/R13 phase D) ----
#pragma unroll
    for (int k = 0; k < NCLS; ++k) {
        part[k * 264 + t]        = acc0[k];
        part[(10 + k) * 264 + t] = acc1[k];
    }
    __syncthreads();

    if (t < 80) {
        const int w2 = t / 20, j = t % 20;
        const float4* src = (const float4*)(part + j * 264 + w2 * 64);
        float4 s4 = src[0];
#pragma unroll
        for (int q = 1; q < 16; ++q) {
            const float4 v = src[q];
            s4.x += v.x; s4.y += v.y; s4.z += v.z; s4.w += v.w;
        }
        const float s = (s4.x + s4.y) + (s4.z + s4.w);
        const int r = j / 10, k = j % 10;
        unsafeAtomicAdd(&out[(rowg * 8 + w2 * 2 + r) * NCLS + k], s);
    }
}

// ---------------------------------------------------------------------------
extern "C" void kernel_launch(void* const* d_in, const int* in_sizes, int n_in,
                              void* d_out, int out_size, void* d_ws, size_t ws_size,
                              hipStream_t stream)
{
    const float* x     = (const float*)d_in[0];
    const float* W_fgl = (const float*)d_in[1];
    const float* b_fgl = (const float*)d_in[2];
    const float* W_fc  = (const float*)d_in[3];
    const float* b_fc  = (const float*)d_in[4];
    const int*   seg   = (const int*)d_in[5];
    float*       out   = (float*)d_out;

    unsigned* AwT32 = (unsigned*)d_ws;     // AwT [10][65536] f16 = 1.31 MB

    awbuild_kernel<<<dim3(PIX / 512),  256, 0, stream>>>(
        W_fgl, b_fgl, W_fc, b_fc, seg, AwT32, out);

    gemm_kernel<<<dim3(NRG * NKC), 256, 0, stream>>>(
        x, (const unsigned short*)AwT32, out);
}